// Round 11
// baseline (59.559 us; speedup 1.0000x reference)
//
#include <hip/hip_runtime.h>
#include <hip/hip_bf16.h>
#include <math.h>

#define B_ 4
#define L_ 2048
#define H_ 8
#define E_ 64
#define HE 512   // H_*E_ : float stride between consecutive seq positions

typedef short bf16x8 __attribute__((ext_vector_type(8)));
typedef float f32x4 __attribute__((ext_vector_type(4)));
typedef float f32x16 __attribute__((ext_vector_type(16)));
typedef unsigned short u16x4 __attribute__((ext_vector_type(4)));
typedef unsigned short u16x8 __attribute__((ext_vector_type(8)));

__device__ __forceinline__ unsigned short f2b(float f) {
  return __builtin_bit_cast(unsigned short, (__hip_bfloat16)f);
}
__device__ __forceinline__ unsigned cvtpk(float lo, float hi) {
  unsigned r;
  asm("v_cvt_pk_bf16_f32 %0, %1, %2" : "=v"(r) : "v"(lo), "v"(hi));
  return r;
}
// operands MUST hold distinct values (R9 lesson: same-value operands can be
// register-coalesced, turning the swap into a self-swap).
__device__ __forceinline__ void pl32swap(unsigned &a, unsigned &b) {
  asm volatile("v_permlane32_swap_b32 %0, %1" : "+v"(a), "+v"(b));
}

// Flash attention fwd, causal, tau-scaled.  UNIFORM-WORK DECOMPOSITION:
// block (hb, j) runs two phases with R5's verified 4-wave inner loop:
//   phase A: q-tile j,    kv tiles [0, j+1)          (j+1 units)
//   phase B: q-tile 15-j, kv tiles [16-j, 32-2j)     (16-j units)
// => every block does exactly 17 serial tile-units (critical chain 17 vs 32),
// 2 uniform blocks co-resident per CU for the whole run (no tail).
// Phase partials (unnormalized O + m,l) -> d_out / d_ws; combine kernel
// merges the two online-softmax states and normalizes.
__global__ __launch_bounds__(256, 2) void attn_fwd(
    const float* __restrict__ Q, const float* __restrict__ K,
    const float* __restrict__ V, const float* __restrict__ tau,
    float* __restrict__ O, float* __restrict__ wsOB,
    float* __restrict__ mA, float* __restrict__ lA,
    float* __restrict__ mB, float* __restrict__ lB)
{
  const int f  = blockIdx.x + 16 * (blockIdx.y + 8 * blockIdx.z);  // 0..511
  const int j  = f >> 5, hb = f & 31;          // (b,h) per f&31 -> XCD-local
  const int h  = hb & 7, b = hb >> 3;

  const int tid  = threadIdx.x;
  const int wave = tid >> 6, lane = tid & 63;
  const int l31 = lane & 31, hi = lane >> 5;
  const int l7 = l31 & 7;

  __shared__ unsigned short ldsK[2][64 * 64];  // [buf][kv][e], swizzled
  __shared__ unsigned short ldsV[2][64 * 64];  // [buf][d][kv], swizzled

  const float qscale = 0.125f * expf(tau[b]) * 1.44269504088896f;

  // staging maps (R5): K: row=tid>>2, chunk (tid&3)*16; V: 4x4 transpose
  const int krow = tid >> 2, kcg = tid & 3;
  const int vkv = (tid & 15) * 4, vd = (tid >> 4) * 4;
  const size_t bh = ((size_t)b * L_ * H_ + h) * E_;
  const int kwo0 = krow * 64 + (((2 * kcg)     ^ (krow & 7)) << 3);
  const int kwo1 = krow * 64 + (((2 * kcg + 1) ^ (krow & 7)) << 3);

  auto stage_write = [&](int nb, const f32x4 (&kq)[4], const f32x4 (&vq)[4]) {
    u16x8 w0, w1;
    #pragma unroll
    for (int jd = 0; jd < 4; ++jd) {
      w0[jd] = f2b(kq[0][jd]); w0[4 + jd] = f2b(kq[1][jd]);
      w1[jd] = f2b(kq[2][jd]); w1[4 + jd] = f2b(kq[3][jd]);
    }
    *(u16x8*)(&ldsK[nb][kwo0]) = w0;
    *(u16x8*)(&ldsK[nb][kwo1]) = w1;
    #pragma unroll
    for (int jd = 0; jd < 4; ++jd) {
      const int row = vd + jd;
      u16x4 vw;
      #pragma unroll
      for (int i = 0; i < 4; ++i) vw[i] = f2b(vq[i][jd]);
      *(u16x4*)(&ldsV[nb][row * 64 + (((vkv >> 3) ^ (row & 7)) << 3) + (vkv & 7)]) = vw;
    }
  };
  auto load_tile = [&](int t, f32x4 (&kq)[4], f32x4 (&vq)[4]) {
    const float* Kn = K + bh + (size_t)(64 * t + krow) * HE + kcg * 16;
    const float* Vn = V + bh + (size_t)(64 * t + vkv) * HE + vd;
    #pragma unroll
    for (int i = 0; i < 4; ++i) kq[i] = *(const f32x4*)(Kn + 4 * i);
    #pragma unroll
    for (int i = 0; i < 4; ++i) vq[i] = *(const f32x4*)(Vn + (size_t)i * HE);
  };

  // ---- one phase: q-tile jj over kv tiles [t0, t1); partial in outputs ----
  auto run_phase = [&](int jj, int t0, int t1,
                       float* Opart, float* mout, float* lout) {
    const int q0w = jj * 128 + wave * 32;
    const int myq = q0w + l31;
    const int tmaxw = 2 * jj + (wave >> 1);    // wave's diagonal tile

    const float* Qb = Q + (((size_t)b * L_ + myq) * H_ + h) * E_;
    bf16x8 qf[4];
    #pragma unroll
    for (int ks = 0; ks < 4; ++ks) {
      f32x4 a = *(const f32x4*)(Qb + ks * 16 + hi * 8);
      f32x4 c = *(const f32x4*)(Qb + ks * 16 + hi * 8 + 4);
      #pragma unroll
      for (int jd = 0; jd < 4; ++jd) {
        qf[ks][jd]     = (short)f2b(a[jd] * qscale);
        qf[ks][4 + jd] = (short)f2b(c[jd] * qscale);
      }
    }

    float m_run = -INFINITY, l_run = 0.0f;
    f32x16 oacc[2];
    #pragma unroll
    for (int nd = 0; nd < 2; ++nd)
      #pragma unroll
      for (int r = 0; r < 16; ++r) oacc[nd][r] = 0.0f;

    f32x4 kq[4], vq[4];
    __syncthreads();                 // prior phase's LDS reads done
    load_tile(t0, kq, vq);
    stage_write(0, kq, vq);
    __syncthreads();
    int cur = 0;

    for (int t = t0; t < t1; ++t) {
      const bool havenext = (t + 1 < t1);
      if (havenext) load_tile(t + 1, kq, vq);  // T14: issue early

      if (t <= tmaxw) {
        const unsigned short* Kl = ldsK[cur];
        const unsigned short* Vl = ldsV[cur];

        // ---- S^T = K Q^T : 8 MFMAs ----
        f32x16 sacc[2];
        #pragma unroll
        for (int mt = 0; mt < 2; ++mt)
          #pragma unroll
          for (int r = 0; r < 16; ++r) sacc[mt][r] = 0.0f;
        __builtin_amdgcn_s_setprio(1);
        #pragma unroll
        for (int ks = 0; ks < 4; ++ks) {
          #pragma unroll
          for (int mt = 0; mt < 2; ++mt) {
            bf16x8 kf = *(const bf16x8*)(Kl + (32 * mt + l31) * 64 +
                                         (((2 * ks + hi) ^ l7) << 3));
            sacc[mt] = __builtin_amdgcn_mfma_f32_32x32x16_bf16(kf, qf[ks], sacc[mt], 0, 0, 0);
          }
        }
        __builtin_amdgcn_s_setprio(0);

        // ---- causal mask (diagonal tile only) ----
        if (t == tmaxw) {
          const int dq = myq - 64 * t;         // keep kv_local <= dq
          #pragma unroll
          for (int mt = 0; mt < 2; ++mt)
            #pragma unroll
            for (int r = 0; r < 16; ++r) {
              const int kvl = 32 * mt + (r & 3) + 8 * (r >> 2) + 4 * hi;
              if (kvl > dq) sacc[mt][r] = -3.0e38f;
            }
        }

        // ---- online softmax: balanced max tree + defer-max (T13) ----
        float p0 = sacc[0][0], p1 = sacc[0][1], p2 = sacc[0][2], p3 = sacc[0][3];
        #pragma unroll
        for (int mt = 0; mt < 2; ++mt)
          #pragma unroll
          for (int r = (mt == 0 ? 4 : 0); r < 16; r += 4) {
            p0 = fmaxf(p0, sacc[mt][r]);
            p1 = fmaxf(p1, sacc[mt][r + 1]);
            p2 = fmaxf(p2, sacc[mt][r + 2]);
            p3 = fmaxf(p3, sacc[mt][r + 3]);
          }
        float mx = fmaxf(fmaxf(p0, p1), fmaxf(p2, p3));
        mx = fmaxf(mx, __shfl_xor(mx, 32));

        if (!__all(mx - m_run <= 8.0f)) {      // rescale needed (rare)
          const float mnew = fmaxf(m_run, mx);
          const float corr = exp2f(m_run - mnew);
          m_run = mnew;
          l_run *= corr;
          #pragma unroll
          for (int r = 0; r < 16; ++r) {
            const int qrow = (r & 3) + 8 * (r >> 2) + 4 * hi;
            const float cr = __shfl(corr, qrow);
            oacc[0][r] *= cr;
            oacc[1][r] *= cr;
          }
        }

        float s0 = 0.f, s1 = 0.f, s2 = 0.f, s3 = 0.f;
        #pragma unroll
        for (int mt = 0; mt < 2; ++mt)
          #pragma unroll
          for (int r = 0; r < 16; r += 4) {
            float e0 = exp2f(sacc[mt][r]     - m_run);
            float e1 = exp2f(sacc[mt][r + 1] - m_run);
            float e2 = exp2f(sacc[mt][r + 2] - m_run);
            float e3 = exp2f(sacc[mt][r + 3] - m_run);
            sacc[mt][r] = e0; sacc[mt][r + 1] = e1;
            sacc[mt][r + 2] = e2; sacc[mt][r + 3] = e3;
            s0 += e0; s1 += e1; s2 += e2; s3 += e3;
          }
        float rs = (s0 + s1) + (s2 + s3);
        rs += __shfl_xor(rs, 32);
        l_run += rs;

        // ---- P -> bf16 packed (T12 step 1) ----
        unsigned pk[2][8];
        #pragma unroll
        for (int mt = 0; mt < 2; ++mt)
          #pragma unroll
          for (int i = 0; i < 8; ++i)
            pk[mt][i] = cvtpk(sacc[mt][2 * i], sacc[mt][2 * i + 1]);

        // ---- O += P V : 8 MFMAs; pf via permlane32_swap (T12 step 2) ----
        __builtin_amdgcn_s_setprio(1);
        #pragma unroll
        for (int ks = 0; ks < 4; ++ks) {
          const int c = ks & 1, mtx = ks >> 1;
          unsigned a  = pk[mtx][4 * c];
          unsigned y  = pk[mtx][4 * c + 2];
          unsigned a2 = pk[mtx][4 * c + 1];
          unsigned y2 = pk[mtx][4 * c + 3];
          pl32swap(a, y);
          pl32swap(a2, y2);
          union { unsigned w[4]; bf16x8 v; } pu;
          pu.w[0] = a; pu.w[1] = a2; pu.w[2] = y; pu.w[3] = y2;
          #pragma unroll
          for (int nd = 0; nd < 2; ++nd) {
            bf16x8 vf = *(const bf16x8*)(Vl + (32 * nd + l31) * 64 +
                                         (((2 * ks + hi) ^ l7) << 3));
            oacc[nd] = __builtin_amdgcn_mfma_f32_32x32x16_bf16(pu.v, vf, oacc[nd], 0, 0, 0);
          }
        }
        __builtin_amdgcn_s_setprio(0);
      }

      if (havenext) {
        stage_write(cur ^ 1, kq, vq);
        __syncthreads();
        cur ^= 1;
      }
    }

    // ---- write unnormalized partial + (m,l) ----
    float* Ob = Opart + (((size_t)b * L_ + q0w) * H_ + h) * E_;
    #pragma unroll
    for (int r = 0; r < 16; ++r) {
      const int qrow = (r & 3) + 8 * (r >> 2) + 4 * hi;
      Ob[(size_t)qrow * HE + l31]      = oacc[0][r];
      Ob[(size_t)qrow * HE + 32 + l31] = oacc[1][r];
    }
    if (hi == 0) {
      const int qh = (b * L_ + q0w + l31) * H_ + h;
      mout[qh] = m_run;
      lout[qh] = l_run;
    }
  };

  run_phase(j, 0, j + 1, O, mA, lA);                    // phase A
  run_phase(15 - j, 16 - j, 32 - 2 * j, wsOB, mB, lB);  // phase B
}

// merge the two online-softmax partials and normalize
__global__ __launch_bounds__(256) void attn_combine(
    float* __restrict__ O, const float* __restrict__ wsOB,
    const float* __restrict__ mA, const float* __restrict__ lA,
    const float* __restrict__ mB, const float* __restrict__ lB)
{
  const int idx = blockIdx.x * 256 + threadIdx.x;       // float4 index
  const int qh = idx >> 4;                              // 16 float4 per row
  const float ma = mA[qh], la = lA[qh];
  const float mb = mB[qh], lb = lB[qh];
  const float m = fmaxf(ma, mb);
  const float wa = exp2f(ma - m), wb = exp2f(mb - m);   // exp2(-inf)=0
  const float inv = 1.0f / (wa * la + wb * lb);
  const f32x4 oa = ((const f32x4*)O)[idx];
  const f32x4 ob = ((const f32x4*)wsOB)[idx];
  f32x4 out;
  #pragma unroll
  for (int i = 0; i < 4; ++i) out[i] = (oa[i] * wa + ob[i] * wb) * inv;
  ((f32x4*)O)[idx] = out;
}

extern "C" void kernel_launch(void* const* d_in, const int* in_sizes, int n_in,
                              void* d_out, int out_size, void* d_ws, size_t ws_size,
                              hipStream_t stream) {
  (void)in_sizes; (void)n_in; (void)out_size; (void)ws_size;
  const float* Q   = (const float*)d_in[0];
  const float* K   = (const float*)d_in[1];
  const float* V   = (const float*)d_in[2];
  // d_in[3] = attn_mask: ignored, causality applied analytically.
  const float* tau = (const float*)d_in[4];
  float* O = (float*)d_out;

  float* wsOB = (float*)d_ws;                    // B*L*H*E f32 = 16.8 MB
  float* mA = wsOB + (size_t)B_ * L_ * H_ * E_;  // B*L*H each
  float* lA = mA + (size_t)B_ * L_ * H_;
  float* mB = lA + (size_t)B_ * L_ * H_;
  float* lB = mB + (size_t)B_ * L_ * H_;

  dim3 grid(16, 8, 4), block(256);
  hipLaunchKernelGGL(attn_fwd, grid, block, 0, stream,
                     Q, K, V, tau, O, wsOB, mA, lA, mB, lB);
  const int total4 = B_ * L_ * H_ * E_ / 4;      // 1,048,576
  hipLaunchKernelGGL(attn_combine, dim3(total4 / 256), dim3(256), 0, stream,
                     O, wsOB, mA, lA, mB, lB);
}